// Round 4
// baseline (452.639 us; speedup 1.0000x reference)
//
#include <hip/hip_runtime.h>

// y[b, c*128+i] = sum_j x[b,c,j]*(R-Q)[i,j] + sum_j S[b,j]*Q[i,j],  S = sum_c x[b,c,:]
// Fused skinny GEMM, K=256, bf16 MFMA 16x16x32.
// R4: grid 512 x block 512 (all WGs resident at t=0 -> R/Q staged from hot L2),
//     16 waves/CU (was 8), dwordx4 stores via in-register 4x4 transpose.

typedef __attribute__((ext_vector_type(4))) float  float4v;
typedef __attribute__((ext_vector_type(4))) float  f32x4;
typedef __attribute__((ext_vector_type(8))) short  short8;

__device__ inline unsigned short f2bf(float f) {
    unsigned u = __builtin_bit_cast(unsigned, f);
    u = (u + 0x7fffu + ((u >> 16) & 1u)) >> 16;   // round-to-nearest-even
    return (unsigned short)u;
}

__global__ __launch_bounds__(512, 4)
void cmix_kernel(const float* __restrict__ x, const float* __restrict__ R,
                 const float* __restrict__ Q, float* __restrict__ y) {
    // B-fragments of W^T (256x128) in MFMA order: WF[kk][n][lane] = 8 bf16,
    // elem j = Wt[kk*32 + (lane>>4)*8 + j][n*16 + (lane&15)]
    __shared__ short8 WF[8][8][64];

    const int tid = threadIdx.x;

    // ---- stage W = [R-Q | Q] into LDS in fragment order (512 WGs, all resident
    //      at launch -> R/Q stay L2-hot; ~1.5 MB compulsory HBM total) ----
    for (int idx = tid; idx < 4096; idx += 512) {
        const int l  = idx & 63;
        const int n  = (idx >> 6) & 7;
        const int kk = idx >> 9;
        const int i  = n * 16 + (l & 15);        // output feature (B-col)
        const int k  = kk * 32 + (l >> 4) * 8;   // K index (multiple of 8)
        short8 v;
        if (k < 128) {  // diagonal-block part: R - Q
            float4v r0 = *(const float4v*)(R + i * 128 + k);
            float4v r1 = *(const float4v*)(R + i * 128 + k + 4);
            float4v q0 = *(const float4v*)(Q + i * 128 + k);
            float4v q1 = *(const float4v*)(Q + i * 128 + k + 4);
#pragma unroll
            for (int j = 0; j < 4; ++j) {
                v[j]     = (short)f2bf(r0[j] - q0[j]);
                v[4 + j] = (short)f2bf(r1[j] - q1[j]);
            }
        } else {        // S part: Q
            float4v q0 = *(const float4v*)(Q + i * 128 + (k - 128));
            float4v q1 = *(const float4v*)(Q + i * 128 + (k - 128) + 4);
#pragma unroll
            for (int j = 0; j < 4; ++j) {
                v[j]     = (short)f2bf(q0[j]);
                v[4 + j] = (short)f2bf(q1[j]);
            }
        }
        WF[kk][n][l] = v;
    }
    __syncthreads();

    const int lane = tid & 63;
    const int w    = tid >> 6;    // 0..7
    const int c16  = lane & 15;   // channel (A-row / M), also B/D column
    const int g    = lane >> 4;   // k-group

    const int b_base = blockIdx.x * 32 + w * 4;

    for (int rr = 0; rr < 4; ++rr) {
        const int b = b_base + rr;
        const float* xr = x + (size_t)b * 2048;

        // ---- A-fragments (x part) straight from global: 8x float4 tile the row
        float4v xa[4][2];
#pragma unroll
        for (int t = 0; t < 4; ++t) {
            const float* p = xr + c16 * 128 + t * 32 + g * 8;
            xa[t][0] = *(const float4v*)(p);
            xa[t][1] = *(const float4v*)(p + 4);
        }

        // ---- pack x frags to bf16; butterfly-reduce 16-lane groups -> S frags
        short8 afr[8];
#pragma unroll
        for (int t = 0; t < 4; ++t) {
            float s[8];
#pragma unroll
            for (int j = 0; j < 8; ++j) s[j] = (j < 4) ? xa[t][0][j] : xa[t][1][j - 4];
            short8 av;
#pragma unroll
            for (int j = 0; j < 8; ++j) av[j] = (short)f2bf(s[j]);
            afr[t] = av;
#pragma unroll
            for (int m = 1; m <= 8; m <<= 1) {
#pragma unroll
                for (int j = 0; j < 8; ++j) s[j] += __shfl_xor(s[j], m, 64);
            }
            short8 sv;
#pragma unroll
            for (int j = 0; j < 8; ++j) sv[j] = (short)f2bf(s[j]);
            afr[4 + t] = sv;   // S[k'] octet, identical across the 16-lane group
        }

        // ---- MFMA: 8 K-steps x 8 N-tiles
        f32x4 acc[8];
#pragma unroll
        for (int n = 0; n < 8; ++n) acc[n] = (f32x4){0.f, 0.f, 0.f, 0.f};
#pragma unroll
        for (int kk = 0; kk < 8; ++kk) {
#pragma unroll
            for (int n = 0; n < 8; ++n) {
                acc[n] = __builtin_amdgcn_mfma_f32_16x16x32_bf16(
                    afr[kk], WF[kk][n][lane], acc[n], 0, 0, 0);
            }
        }

        // ---- 4x4 lane transpose within quads (lane bits 0-1), then dwordx4 store.
        // D layout: acc[n][r] = y_tile[row 4g+r][col n*16+c16]. After transpose,
        // lane (g, c16=4a+s) reg r = y_tile[row 4g+s][col n*16+4a+r].
        float* yr = y + (size_t)b * 2048;
        const int s4 = lane & 3;
        const int a4 = (lane >> 2) & 3;
#pragma unroll
        for (int n = 0; n < 8; ++n) {
            f32x4 v = acc[n];
            {   // stage 1: exchange across lane bit 0, reg pairs (0,1) and (2,3)
                float A0 = v[0], B0 = v[1], A1 = v[2], B1 = v[3];
                float o0 = __shfl_xor((lane & 1) ? A0 : B0, 1, 64);
                float o1 = __shfl_xor((lane & 1) ? A1 : B1, 1, 64);
                if (lane & 1) { v[0] = o0; v[2] = o1; }
                else          { v[1] = o0; v[3] = o1; }
            }
            {   // stage 2: exchange across lane bit 1, reg pairs (0,2) and (1,3)
                float A0 = v[0], B0 = v[2], A1 = v[1], B1 = v[3];
                float o0 = __shfl_xor((lane & 2) ? A0 : B0, 2, 64);
                float o1 = __shfl_xor((lane & 2) ? A1 : B1, 2, 64);
                if (lane & 2) { v[0] = o0; v[1] = o1; }
                else          { v[2] = o0; v[3] = o1; }
            }
            *(float4v*)(yr + (g * 4 + s4) * 128 + n * 16 + a4 * 4) = v;
        }
    }
}

extern "C" void kernel_launch(void* const* d_in, const int* in_sizes, int n_in,
                              void* d_out, int out_size, void* d_ws, size_t ws_size,
                              hipStream_t stream) {
    const float* x = (const float*)d_in[0];
    const float* R = (const float*)d_in[1];
    const float* Q = (const float*)d_in[2];
    float* y = (float*)d_out;
    // B=16384 rows, 32 rows per WG (8 waves x 4 rows), grid = 512 (2 WG/CU, all resident)
    hipLaunchKernelGGL(cmix_kernel, dim3(512), dim3(512), 0, stream, x, R, Q, y);
}

// Round 5
// 245.049 us; speedup vs baseline: 1.8471x; 1.8471x over previous
//
#include <hip/hip_runtime.h>

// y[b, c*128+i] = sum_j x[b,c,j]*(R-Q)[i,j] + sum_j S[b,j]*Q[i,j],  S = sum_c x[b,c,:]
// R5: S-term via second MFMA chain (x·Q^T) + cheap D-tile row-sum (3 add + 2 shfl
//     per n-tile) instead of the 128-shfl butterfly. waves_per_eu(4,4) pins the
//     VGPR budget at 128 (R4's (512,4) let the compiler squeeze to 64 -> spills,
//     +265 MB HBM). Nontemporal x/y streams keep R/Q L2-resident.

typedef __attribute__((ext_vector_type(4))) float  float4v;
typedef __attribute__((ext_vector_type(4))) float  f32x4;
typedef __attribute__((ext_vector_type(8))) short  short8;

__device__ inline unsigned short f2bf(float f) {
    unsigned u = __builtin_bit_cast(unsigned, f);
    u = (u + 0x7fffu + ((u >> 16) & 1u)) >> 16;   // round-to-nearest-even
    return (unsigned short)u;
}

__global__ void
__attribute__((amdgpu_flat_work_group_size(512, 512), amdgpu_waves_per_eu(4, 4)))
cmix_kernel(const float* __restrict__ x, const float* __restrict__ R,
            const float* __restrict__ Q, float* __restrict__ y) {
    // B-fragments in MFMA order: W*[kk][n][lane] elem j = W[n*16+(lane&15)][kk*32+(lane>>4)*8+j]
    __shared__ short8 WA[4][8][64];   // R - Q   (diagonal blocks)
    __shared__ short8 WB[4][8][64];   // Q       (S term)

    const int tid = threadIdx.x;

    // ---- stage both weight arrays (all 512 WGs resident at t=0 -> L2-hot) ----
    for (int idx = tid; idx < 4096; idx += 512) {
        const int l  = idx & 63;
        const int n  = (idx >> 6) & 7;
        const int kk = idx >> 9;                  // 0..7 ; 0-3 -> WA, 4-7 -> WB
        const int i  = n * 16 + (l & 15);         // output feature
        const int k  = (kk & 3) * 32 + (l >> 4) * 8;
        const float4v q0 = *(const float4v*)(Q + i * 128 + k);
        const float4v q1 = *(const float4v*)(Q + i * 128 + k + 4);
        short8 v;
        if (kk < 4) {
            const float4v r0 = *(const float4v*)(R + i * 128 + k);
            const float4v r1 = *(const float4v*)(R + i * 128 + k + 4);
#pragma unroll
            for (int j = 0; j < 4; ++j) {
                v[j]     = (short)f2bf(r0[j] - q0[j]);
                v[4 + j] = (short)f2bf(r1[j] - q1[j]);
            }
            WA[kk][n][l] = v;
        } else {
#pragma unroll
            for (int j = 0; j < 4; ++j) {
                v[j]     = (short)f2bf(q0[j]);
                v[4 + j] = (short)f2bf(q1[j]);
            }
            WB[kk - 4][n][l] = v;
        }
    }
    __syncthreads();

    const int lane = tid & 63;
    const int w    = tid >> 6;    // 0..7
    const int c16  = lane & 15;   // channel (A-row / M), also B/D column
    const int g    = lane >> 4;   // k-group
    const int s4   = lane & 3;
    const int a4   = (lane >> 2) & 3;

    const int b_base = blockIdx.x * 32 + w * 4;

    for (int rr = 0; rr < 4; ++rr) {
        const int b = b_base + rr;
        const float* xr = x + (size_t)b * 2048;

        // ---- A-fragments straight from global (nontemporal: zero reuse) ----
        float4v xa[4][2];
#pragma unroll
        for (int t = 0; t < 4; ++t) {
            const float* p = xr + c16 * 128 + t * 32 + g * 8;
            xa[t][0] = __builtin_nontemporal_load((const float4v*)p);
            xa[t][1] = __builtin_nontemporal_load((const float4v*)p + 1);
        }

        // ---- pack to bf16 fragments (no butterfly) ----
        short8 afr[4];
#pragma unroll
        for (int t = 0; t < 4; ++t) {
            short8 av;
#pragma unroll
            for (int j = 0; j < 4; ++j) {
                av[j]     = (short)f2bf(xa[t][0][j]);
                av[4 + j] = (short)f2bf(xa[t][1][j]);
            }
            afr[t] = av;
        }

        // ---- per n-tile: ad = x·(R-Q)^T, aq = x·Q^T ; Sq = row-sum(aq) ----
        float* yr = y + (size_t)b * 2048;
#pragma unroll 2
        for (int n = 0; n < 8; ++n) {
            f32x4 ad = (f32x4){0.f, 0.f, 0.f, 0.f};
            f32x4 aq = (f32x4){0.f, 0.f, 0.f, 0.f};
#pragma unroll
            for (int kk = 0; kk < 4; ++kk) {
                ad = __builtin_amdgcn_mfma_f32_16x16x32_bf16(afr[kk], WA[kk][n][lane], ad, 0, 0, 0);
                aq = __builtin_amdgcn_mfma_f32_16x16x32_bf16(afr[kk], WB[kk][n][lane], aq, 0, 0, 0);
            }
            // Sq[col=c16] = sum over all 16 rows of aq tile (rows live across g,r)
            float sq = (aq[0] + aq[1]) + (aq[2] + aq[3]);
            sq += __shfl_xor(sq, 16, 64);
            sq += __shfl_xor(sq, 32, 64);

            f32x4 v;
#pragma unroll
            for (int r = 0; r < 4; ++r) v[r] = ad[r] + sq;

            // 4x4 lane transpose within quads -> dwordx4 store (verified in R4)
            {   // stage 1: exchange across lane bit 0, reg pairs (0,1) and (2,3)
                float A0 = v[0], B0 = v[1], A1 = v[2], B1 = v[3];
                float o0 = __shfl_xor((lane & 1) ? A0 : B0, 1, 64);
                float o1 = __shfl_xor((lane & 1) ? A1 : B1, 1, 64);
                if (lane & 1) { v[0] = o0; v[2] = o1; }
                else          { v[1] = o0; v[3] = o1; }
            }
            {   // stage 2: exchange across lane bit 1, reg pairs (0,2) and (1,3)
                float A0 = v[0], B0 = v[2], A1 = v[1], B1 = v[3];
                float o0 = __shfl_xor((lane & 2) ? A0 : B0, 2, 64);
                float o1 = __shfl_xor((lane & 2) ? A1 : B1, 2, 64);
                if (lane & 2) { v[0] = o0; v[1] = o1; }
                else          { v[2] = o0; v[3] = o1; }
            }
            __builtin_nontemporal_store(v, (float4v*)(yr + (g * 4 + s4) * 128 + n * 16 + a4 * 4));
        }
    }
}

extern "C" void kernel_launch(void* const* d_in, const int* in_sizes, int n_in,
                              void* d_out, int out_size, void* d_ws, size_t ws_size,
                              hipStream_t stream) {
    const float* x = (const float*)d_in[0];
    const float* R = (const float*)d_in[1];
    const float* Q = (const float*)d_in[2];
    float* y = (float*)d_out;
    // 32 rows per WG (8 waves x 4 rows), grid = 512 (2 WG/CU, all resident)
    hipLaunchKernelGGL(cmix_kernel, dim3(512), dim3(512), 0, stream, x, R, Q, y);
}